// Round 8
// baseline (3631.834 us; speedup 1.0000x reference)
//
#include <hip/hip_runtime.h>
#include <hip/hip_bf16.h>

// GetPseudoMaskSLFCAMS: exact rank-cut selection (stable ties) + 3x3 dilation + seed map.
// x: (128,1,512,512) fp32.  out: (128,512,512) int32 {1,0,-255}  (harness reads np.int32).
//
// Key identity: jnp.argsort is stable ascending, so
//   bg(q)  <=> (u(x_q), idx_q) <= boundary key at rank MIN_-1   (rank 26213)
//   fg(q)  <=> (u(x_q), idx_q) >= boundary key at rank HW-MAX_  (rank 235930)
// where u() is the sign-flip monotone float->u32 map.

#define HW      262144      // 512*512 = 2^18
#define NROW    128
#define R1_RANK 26213u      // MIN_-1
#define R2_RANK 235930u     // HW-MAX_
#define NBIN    8192        // top-13 bits of sortable u32
#define CAP     8192        // candidate capacity per (row,side); max expected ~4K for N(0,1)
#define LCAP    1024        // third-level list capacity

__device__ __forceinline__ unsigned f2u(float f) {
    unsigned b = __float_as_uint(f);
    return b ^ ((b >> 31) ? 0xFFFFFFFFu : 0x80000000u);
}

// ---------------- K1: per-row coarse histogram (top 13 bits) ----------------
// 8 chunks/row -> 1024 blocks -> 4 blocks/CU (16 waves/CU) to hide HBM latency.
__global__ __launch_bounds__(256) void k_hist(const float* __restrict__ x,
                                              unsigned* __restrict__ hist) {
    __shared__ unsigned lh[NBIN];
    for (int i = threadIdx.x; i < NBIN; i += 256) lh[i] = 0;
    __syncthreads();
    int row = blockIdx.x >> 3;    // 8 chunks/row
    int chunk = blockIdx.x & 7;
    const float4* p = (const float4*)(x + (size_t)row * HW + (size_t)chunk * 32768);
    for (int it = 0; it < 32; ++it) {
        float4 v = p[it * 256 + threadIdx.x];
        atomicAdd(&lh[f2u(v.x) >> 19], 1u);
        atomicAdd(&lh[f2u(v.y) >> 19], 1u);
        atomicAdd(&lh[f2u(v.z) >> 19], 1u);
        atomicAdd(&lh[f2u(v.w) >> 19], 1u);
    }
    __syncthreads();
    unsigned* gh = hist + (size_t)row * NBIN;
    for (int i = threadIdx.x; i < NBIN; i += 256) {
        unsigned c = lh[i];
        if (c) atomicAdd(&gh[i], c);
    }
}

// ---------------- K2: find bin containing each rank + within-bin rank -------
// meta[row*4 + {0,1,2,3}] = {bin1, r1, bin2, r2}
__global__ __launch_bounds__(256) void k_findbin(const unsigned* __restrict__ hist,
                                                 unsigned* __restrict__ meta) {
    int row = blockIdx.x;
    const unsigned* h = hist + (size_t)row * NBIN;
    __shared__ unsigned psum[256];
    __shared__ unsigned excl[257];
    int base = threadIdx.x * 32;
    unsigned s = 0;
    for (int i = 0; i < 32; ++i) s += h[base + i];
    psum[threadIdx.x] = s;
    __syncthreads();
    if (threadIdx.x == 0) {
        unsigned a = 0;
        for (int t = 0; t < 256; ++t) { excl[t] = a; a += psum[t]; }
        excl[256] = a;
    }
    __syncthreads();
    for (int side = 0; side < 2; ++side) {
        unsigned R = side ? R2_RANK : R1_RANK;
        if (excl[threadIdx.x] <= R && R < excl[threadIdx.x + 1]) {
            unsigned a = excl[threadIdx.x];
            for (int i = 0; i < 32; ++i) {
                unsigned c = h[base + i];
                if (R < a + c) { meta[row * 4 + side * 2] = base + i;
                                 meta[row * 4 + side * 2 + 1] = R - a; break; }
                a += c;
            }
        }
    }
}

// ---------------- K3: collect candidates in boundary bins -------------------
__global__ __launch_bounds__(256) void k_collect(const float* __restrict__ x,
                                                 const unsigned* __restrict__ meta,
                                                 unsigned* __restrict__ cnt,
                                                 unsigned long long* __restrict__ cand) {
    size_t i4 = (size_t)blockIdx.x * 256 + threadIdx.x;   // float4 index
    size_t base = i4 * 4;
    int row = (int)(base >> 18);
    unsigned bin1 = meta[row * 4 + 0];
    unsigned bin2 = meta[row * 4 + 2];
    float4 v = ((const float4*)x)[i4];
    float vv[4] = {v.x, v.y, v.z, v.w};
    int lane = threadIdx.x & 63;
    unsigned long long lowmask = (lane == 0) ? 0ull : ((1ull << lane) - 1ull);
    for (int k = 0; k < 4; ++k) {
        unsigned u = f2u(vv[k]);
        unsigned bin = u >> 19;
        unsigned idx = (unsigned)(base + k) & (HW - 1);
        for (int side = 0; side < 2; ++side) {
            bool p = (bin == (side ? bin2 : bin1));
            unsigned long long m = __ballot(p);   // wave-uniform (row is wave-uniform)
            if (m) {
                int leader = __ffsll((long long)m) - 1;
                unsigned bc = 0;
                if (lane == leader)
                    bc = atomicAdd(&cnt[row * 2 + side], (unsigned)__popcll(m));
                bc = (unsigned)__shfl((int)bc, leader, 64);
                unsigned off = (unsigned)__popcll(m & lowmask);
                if (p) {
                    unsigned slot = bc + off;
                    if (slot < CAP)
                        cand[((size_t)(row * 2 + side)) * CAP + slot] =
                            (((unsigned long long)u) << 32) | idx;
                }
            }
        }
    }
}

// ---------------- K4: exact boundary key per (row,side) ---------------------
// thr[row*4 + {0,1,2,3}] = {T1u, cutIdx1, T2u, cutIdx2}
__global__ __launch_bounds__(256) void k_select(const unsigned* __restrict__ meta,
                                                const unsigned* __restrict__ cnt,
                                                const unsigned long long* __restrict__ cand,
                                                unsigned* __restrict__ thr) {
    int row = blockIdx.x >> 1, side = blockIdx.x & 1;
    unsigned m = cnt[row * 2 + side]; if (m > CAP) m = CAP;
    unsigned r = meta[row * 4 + side * 2 + 1];
    const unsigned long long* ck = cand + ((size_t)(row * 2 + side)) * CAP;

    __shared__ unsigned h2[NBIN];
    __shared__ unsigned psum[256];
    __shared__ unsigned excl[257];
    __shared__ unsigned long long list[LCAP];
    __shared__ unsigned listCnt, subbin_s, rprime_s;
    for (int i = threadIdx.x; i < NBIN; i += 256) h2[i] = 0;
    if (threadIdx.x == 0) listCnt = 0;
    __syncthreads();
    // second-level histogram over bits 18..6 (all candidates share bits 31..19)
    for (unsigned i = threadIdx.x; i < m; i += 256) {
        unsigned u = (unsigned)(ck[i] >> 32);
        atomicAdd(&h2[(u >> 6) & (NBIN - 1)], 1u);
    }
    __syncthreads();
    int base = threadIdx.x * 32;
    unsigned s = 0;
    for (int i = 0; i < 32; ++i) s += h2[base + i];
    psum[threadIdx.x] = s;
    __syncthreads();
    if (threadIdx.x == 0) {
        unsigned a = 0;
        for (int t = 0; t < 256; ++t) { excl[t] = a; a += psum[t]; }
        excl[256] = a;
    }
    __syncthreads();
    if (excl[threadIdx.x] <= r && r < excl[threadIdx.x + 1]) {
        unsigned a = excl[threadIdx.x];
        for (int i = 0; i < 32; ++i) {
            unsigned c = h2[base + i];
            if (r < a + c) { subbin_s = (unsigned)(base + i); rprime_s = r - a; break; }
            a += c;
        }
    }
    __syncthreads();
    unsigned sb = subbin_s, rp = rprime_s;
    // third level: gather the (few) keys in the cut sub-bin, exact rank among them
    for (unsigned i = threadIdx.x; i < m; i += 256) {
        unsigned long long k = ck[i];
        if ((((unsigned)(k >> 32)) >> 6 & (NBIN - 1)) == sb) {
            unsigned slot = atomicAdd(&listCnt, 1u);
            if (slot < LCAP) list[slot] = k;
        }
    }
    __syncthreads();
    unsigned lm = listCnt; if (lm > LCAP) lm = LCAP;
    for (unsigned i = threadIdx.x; i < lm; i += 256) {
        unsigned long long ki = list[i];
        unsigned c = 0;
        for (unsigned j = 0; j < lm; ++j) c += (list[j] < ki);
        if (c == rp) {
            thr[row * 4 + side * 2]     = (unsigned)(ki >> 32);
            thr[row * 4 + side * 2 + 1] = (unsigned)ki;
        }
    }
}

// ---------------- K5: fused seed codes + 3x3 dilation + int32 output --------
__global__ __launch_bounds__(256) void k_seed(const float* __restrict__ x,
                                              const unsigned* __restrict__ thr,
                                              int* __restrict__ out) {
    int row = blockIdx.z;
    int tx0 = blockIdx.x * 32, ty0 = blockIdx.y * 32;
    __shared__ unsigned char code[34 * 36];   // [ly][lx], stride 36
    unsigned T1 = thr[row * 4 + 0], C1 = thr[row * 4 + 1];
    unsigned T2 = thr[row * 4 + 2], C2 = thr[row * 4 + 3];
    const float* xr = x + (size_t)row * HW;
    for (int t = threadIdx.x; t < 34 * 34; t += 256) {
        int ly = t / 34, lx = t % 34;
        int gy = ty0 + ly - 1, gx = tx0 + lx - 1;
        unsigned char c = 0;
        if (gx >= 0 && gx < 512 && gy >= 0 && gy < 512) {
            unsigned idx = (unsigned)(gy * 512 + gx);
            unsigned u = f2u(xr[idx]);
            bool bg = (u < T1) || (u == T1 && idx <= C1);
            bool fg = (u > T2) || (u == T2 && idx >= C2);
            c = (unsigned char)((bg ? 1 : 0) | (fg ? 2 : 0));
        }
        code[ly * 36 + lx] = c;
    }
    __syncthreads();
    int lx = threadIdx.x & 31;
    int ly0 = (threadIdx.x >> 5) * 4;
    // rolling column-OR: colOR(r) = OR of code[r][lx..lx+2]; 3x3 OR = colOR over 3 rows
    #define OR3(r) ((unsigned)(code[(r) * 36 + lx] | code[(r) * 36 + lx + 1] | code[(r) * 36 + lx + 2]))
    unsigned c0 = OR3(ly0), c1 = OR3(ly0 + 1);
    for (int k = 0; k < 4; ++k) {
        unsigned c2 = OR3(ly0 + k + 2);
        unsigned mm = c0 | c1 | c2;
        bool bgd = mm & 1, fgd = mm & 2;
        // int32 output: fg-only -> 1; bg-only -> 0; both or neither -> -255
        int o = ((bgd ^ fgd) != 0) ? (fgd ? 1 : 0) : -255;
        out[(size_t)row * HW + (size_t)(ty0 + ly0 + k) * 512 + (tx0 + lx)] = o;
        c0 = c1; c1 = c2;
    }
    #undef OR3
}

extern "C" void kernel_launch(void* const* d_in, const int* in_sizes, int n_in,
                              void* d_out, int out_size, void* d_ws, size_t ws_size,
                              hipStream_t stream) {
    const float* x = (const float*)d_in[0];
    int* out = (int*)d_out;

    // workspace layout (needs ~21 MB)
    char* ws = (char*)d_ws;
    unsigned* hist = (unsigned*)ws;                                   // 4 MB
    unsigned* cnt  = (unsigned*)(ws + (size_t)NROW * NBIN * 4);       // 1 KB
    unsigned* meta = (unsigned*)(ws + (size_t)NROW * NBIN * 4 + 1024);          // 2 KB
    unsigned* thr  = (unsigned*)(ws + (size_t)NROW * NBIN * 4 + 3072);          // 2 KB
    unsigned long long* cand =
        (unsigned long long*)(ws + (size_t)NROW * NBIN * 4 + 8192);   // 16 MB

    // zero hist + counters (contiguous prefix of ws)
    hipMemsetAsync(d_ws, 0, (size_t)NROW * NBIN * 4 + 1024, stream);

    k_hist<<<NROW * 8, 256, 0, stream>>>(x, hist);
    k_findbin<<<NROW, 256, 0, stream>>>(hist, meta);
    k_collect<<<(NROW * HW) / (256 * 4), 256, 0, stream>>>(x, meta, cnt, cand);
    k_select<<<NROW * 2, 256, 0, stream>>>(meta, cnt, cand, thr);
    k_seed<<<dim3(16, 16, NROW), 256, 0, stream>>>(x, thr, out);
}

// Round 11
// 392.041 us; speedup vs baseline: 9.2639x; 9.2639x over previous
//
#include <hip/hip_runtime.h>
#include <hip/hip_bf16.h>

// GetPseudoMaskSLFCAMS: exact rank-cut selection (stable ties) + 3x3 dilation + seed map.
// x: (128,1,512,512) fp32.  out: (128,512,512) int32 {1,0,-255}.
//
//   bg(q)  <=> (u(x_q), idx_q) <= boundary key at rank 26213
//   fg(q)  <=> (u(x_q), idx_q) >= boundary key at rank 235930
// u() = sign-flip monotone float->u32 map.

#define HW      262144      // 512*512 = 2^18
#define NROW    128
#define R1_RANK 26213u      // MIN_-1
#define R2_RANK 235930u     // HW-MAX_
#define NBIN    8192        // top-13 bits of sortable u32
#define CAP     8192        // candidate capacity per (row,side); expected ~2.9K for N(0,1)
#define LCAP    1024        // third-level list capacity
#define CBLK    2048        // elements per k_collect block

__device__ __forceinline__ unsigned f2u(float f) {
    unsigned b = __float_as_uint(f);
    return b ^ ((b >> 31) ? 0xFFFFFFFFu : 0x80000000u);
}

// ---------------- K1: per-row coarse histogram (top 13 bits) ----------------
__global__ __launch_bounds__(256) void k_hist(const float* __restrict__ x,
                                              unsigned* __restrict__ hist) {
    __shared__ unsigned lh[NBIN];
    for (int i = threadIdx.x; i < NBIN; i += 256) lh[i] = 0;
    __syncthreads();
    int row = blockIdx.x >> 3;    // 8 chunks/row
    int chunk = blockIdx.x & 7;
    const float4* p = (const float4*)(x + (size_t)row * HW + (size_t)chunk * 32768);
    for (int it = 0; it < 32; ++it) {
        float4 v = p[it * 256 + threadIdx.x];
        atomicAdd(&lh[f2u(v.x) >> 19], 1u);
        atomicAdd(&lh[f2u(v.y) >> 19], 1u);
        atomicAdd(&lh[f2u(v.z) >> 19], 1u);
        atomicAdd(&lh[f2u(v.w) >> 19], 1u);
    }
    __syncthreads();
    unsigned* gh = hist + (size_t)row * NBIN;
    for (int i = threadIdx.x; i < NBIN; i += 256) {
        unsigned c = lh[i];
        if (c) atomicAdd(&gh[i], c);
    }
}

// ---------------- K2: find bin containing each rank + within-bin rank -------
// meta[row*4 + {0,1,2,3}] = {bin1, r1, bin2, r2}
__global__ __launch_bounds__(256) void k_findbin(const unsigned* __restrict__ hist,
                                                 unsigned* __restrict__ meta) {
    int row = blockIdx.x;
    const unsigned* h = hist + (size_t)row * NBIN;
    __shared__ unsigned psum[256];
    __shared__ unsigned excl[257];
    int base = threadIdx.x * 32;
    unsigned s = 0;
    for (int i = 0; i < 32; ++i) s += h[base + i];
    psum[threadIdx.x] = s;
    __syncthreads();
    if (threadIdx.x == 0) {
        unsigned a = 0;
        for (int t = 0; t < 256; ++t) { excl[t] = a; a += psum[t]; }
        excl[256] = a;
    }
    __syncthreads();
    for (int side = 0; side < 2; ++side) {
        unsigned R = side ? R2_RANK : R1_RANK;
        if (excl[threadIdx.x] <= R && R < excl[threadIdx.x + 1]) {
            unsigned a = excl[threadIdx.x];
            for (int i = 0; i < 32; ++i) {
                unsigned c = h[base + i];
                if (R < a + c) { meta[row * 4 + side * 2] = base + i;
                                 meta[row * 4 + side * 2 + 1] = R - a; break; }
                a += c;
            }
        }
    }
}

// ---------------- K3: collect candidates (block-aggregated, 2 atomics/block) -
__global__ __launch_bounds__(256) void k_collect(const float* __restrict__ x,
                                                 const unsigned* __restrict__ meta,
                                                 unsigned* __restrict__ cnt,
                                                 unsigned long long* __restrict__ cand) {
    __shared__ unsigned long long buf0[CBLK];
    __shared__ unsigned long long buf1[CBLK];
    __shared__ unsigned bcnt[2];
    __shared__ unsigned gbase[2];
    if (threadIdx.x < 2) bcnt[threadIdx.x] = 0;
    __syncthreads();

    size_t ebase = (size_t)blockIdx.x * CBLK;     // block-aligned, row-uniform
    int row = (int)(ebase >> 18);
    unsigned bin1 = meta[row * 4 + 0];
    unsigned bin2 = meta[row * 4 + 2];
    const float4* p = (const float4*)(x + ebase);
    #pragma unroll
    for (int j = 0; j < 2; ++j) {
        int t4 = j * 256 + threadIdx.x;
        float4 v = p[t4];
        float vv[4] = {v.x, v.y, v.z, v.w};
        unsigned eidx = (unsigned)((ebase + (size_t)t4 * 4) & (HW - 1));
        #pragma unroll
        for (int k = 0; k < 4; ++k) {
            unsigned u = f2u(vv[k]);
            unsigned bin = u >> 19;
            unsigned long long key = (((unsigned long long)u) << 32) | (eidx + k);
            if (bin == bin1) buf0[atomicAdd(&bcnt[0], 1u)] = key;
            if (bin == bin2) buf1[atomicAdd(&bcnt[1], 1u)] = key;
        }
    }
    __syncthreads();
    if (threadIdx.x < 2)
        gbase[threadIdx.x] = atomicAdd(&cnt[row * 2 + threadIdx.x], bcnt[threadIdx.x]);
    __syncthreads();
    unsigned n0 = bcnt[0], n1 = bcnt[1];
    unsigned long long* c0 = cand + ((size_t)(row * 2 + 0)) * CAP;
    unsigned long long* c1 = cand + ((size_t)(row * 2 + 1)) * CAP;
    for (unsigned i = threadIdx.x; i < n0; i += 256) {
        unsigned slot = gbase[0] + i;
        if (slot < CAP) c0[slot] = buf0[i];
    }
    for (unsigned i = threadIdx.x; i < n1; i += 256) {
        unsigned slot = gbase[1] + i;
        if (slot < CAP) c1[slot] = buf1[i];
    }
}

// ---------------- K4: exact boundary key per (row,side) ---------------------
// thr[row*4 + {0,1,2,3}] = {T1u, cutIdx1, T2u, cutIdx2}
__global__ __launch_bounds__(256) void k_select(const unsigned* __restrict__ meta,
                                                const unsigned* __restrict__ cnt,
                                                const unsigned long long* __restrict__ cand,
                                                unsigned* __restrict__ thr) {
    int row = blockIdx.x >> 1, side = blockIdx.x & 1;
    unsigned m = cnt[row * 2 + side]; if (m > CAP) m = CAP;
    unsigned r = meta[row * 4 + side * 2 + 1];
    const unsigned long long* ck = cand + ((size_t)(row * 2 + side)) * CAP;

    __shared__ unsigned h2[NBIN];
    __shared__ unsigned psum[256];
    __shared__ unsigned excl[257];
    __shared__ unsigned long long list[LCAP];
    __shared__ unsigned listCnt, subbin_s, rprime_s;
    for (int i = threadIdx.x; i < NBIN; i += 256) h2[i] = 0;
    if (threadIdx.x == 0) listCnt = 0;
    __syncthreads();
    // second-level histogram over bits 18..6 (all candidates share bits 31..19)
    for (unsigned i = threadIdx.x; i < m; i += 256) {
        unsigned u = (unsigned)(ck[i] >> 32);
        atomicAdd(&h2[(u >> 6) & (NBIN - 1)], 1u);
    }
    __syncthreads();
    int base = threadIdx.x * 32;
    unsigned s = 0;
    for (int i = 0; i < 32; ++i) s += h2[base + i];
    psum[threadIdx.x] = s;
    __syncthreads();
    if (threadIdx.x == 0) {
        unsigned a = 0;
        for (int t = 0; t < 256; ++t) { excl[t] = a; a += psum[t]; }
        excl[256] = a;
    }
    __syncthreads();
    if (excl[threadIdx.x] <= r && r < excl[threadIdx.x + 1]) {
        unsigned a = excl[threadIdx.x];
        for (int i = 0; i < 32; ++i) {
            unsigned c = h2[base + i];
            if (r < a + c) { subbin_s = (unsigned)(base + i); rprime_s = r - a; break; }
            a += c;
        }
    }
    __syncthreads();
    unsigned sb = subbin_s, rp = rprime_s;
    // third level: gather the (few) keys in the cut sub-bin, exact rank among them
    for (unsigned i = threadIdx.x; i < m; i += 256) {
        unsigned long long k = ck[i];
        if ((((unsigned)(k >> 32)) >> 6 & (NBIN - 1)) == sb) {
            unsigned slot = atomicAdd(&listCnt, 1u);
            if (slot < LCAP) list[slot] = k;
        }
    }
    __syncthreads();
    unsigned lm = listCnt; if (lm > LCAP) lm = LCAP;
    for (unsigned i = threadIdx.x; i < lm; i += 256) {
        unsigned long long ki = list[i];
        unsigned c = 0;
        for (unsigned j = 0; j < lm; ++j) c += (list[j] < ki);
        if (c == rp) {
            thr[row * 4 + side * 2]     = (unsigned)(ki >> 32);
            thr[row * 4 + side * 2 + 1] = (unsigned)ki;
        }
    }
}

// ---------------- K5: fused seed codes + 3x3 dilation + int32 output --------
__global__ __launch_bounds__(256) void k_seed(const float* __restrict__ x,
                                              const unsigned* __restrict__ thr,
                                              int* __restrict__ out) {
    int row = blockIdx.z;
    int tx0 = blockIdx.x * 32, ty0 = blockIdx.y * 32;
    __shared__ unsigned char code[34 * 36];   // [ly][lx], stride 36
    unsigned T1 = thr[row * 4 + 0], C1 = thr[row * 4 + 1];
    unsigned T2 = thr[row * 4 + 2], C2 = thr[row * 4 + 3];
    const float* xr = x + (size_t)row * HW;
    for (int t = threadIdx.x; t < 34 * 34; t += 256) {
        int ly = t / 34, lx = t % 34;
        int gy = ty0 + ly - 1, gx = tx0 + lx - 1;
        unsigned char c = 0;
        if (gx >= 0 && gx < 512 && gy >= 0 && gy < 512) {
            unsigned idx = (unsigned)(gy * 512 + gx);
            unsigned u = f2u(xr[idx]);
            bool bg = (u < T1) || (u == T1 && idx <= C1);
            bool fg = (u > T2) || (u == T2 && idx >= C2);
            c = (unsigned char)((bg ? 1 : 0) | (fg ? 2 : 0));
        }
        code[ly * 36 + lx] = c;
    }
    __syncthreads();
    int lx = threadIdx.x & 31;
    int ly0 = (threadIdx.x >> 5) * 4;
    #define OR3(r) ((unsigned)(code[(r) * 36 + lx] | code[(r) * 36 + lx + 1] | code[(r) * 36 + lx + 2]))
    unsigned c0 = OR3(ly0), c1 = OR3(ly0 + 1);
    for (int k = 0; k < 4; ++k) {
        unsigned c2 = OR3(ly0 + k + 2);
        unsigned mm = c0 | c1 | c2;
        bool bgd = mm & 1, fgd = mm & 2;
        int o = ((bgd ^ fgd) != 0) ? (fgd ? 1 : 0) : -255;
        out[(size_t)row * HW + (size_t)(ty0 + ly0 + k) * 512 + (tx0 + lx)] = o;
        c0 = c1; c1 = c2;
    }
    #undef OR3
}

extern "C" void kernel_launch(void* const* d_in, const int* in_sizes, int n_in,
                              void* d_out, int out_size, void* d_ws, size_t ws_size,
                              hipStream_t stream) {
    const float* x = (const float*)d_in[0];
    int* out = (int*)d_out;

    // workspace layout (needs ~21 MB)
    char* ws = (char*)d_ws;
    unsigned* hist = (unsigned*)ws;                                   // 4 MB
    unsigned* cnt  = (unsigned*)(ws + (size_t)NROW * NBIN * 4);       // 1 KB
    unsigned* meta = (unsigned*)(ws + (size_t)NROW * NBIN * 4 + 1024);          // 2 KB
    unsigned* thr  = (unsigned*)(ws + (size_t)NROW * NBIN * 4 + 3072);          // 2 KB
    unsigned long long* cand =
        (unsigned long long*)(ws + (size_t)NROW * NBIN * 4 + 8192);   // 16 MB

    // zero hist + counters (contiguous prefix of ws)
    hipMemsetAsync(d_ws, 0, (size_t)NROW * NBIN * 4 + 1024, stream);

    k_hist<<<NROW * 8, 256, 0, stream>>>(x, hist);
    k_findbin<<<NROW, 256, 0, stream>>>(hist, meta);
    k_collect<<<(NROW * HW) / CBLK, 256, 0, stream>>>(x, meta, cnt, cand);
    k_select<<<NROW * 2, 256, 0, stream>>>(meta, cnt, cand, thr);
    k_seed<<<dim3(16, 16, NROW), 256, 0, stream>>>(x, thr, out);
}

// Round 13
// 383.839 us; speedup vs baseline: 9.4619x; 1.0214x over previous
//
#include <hip/hip_runtime.h>
#include <hip/hip_bf16.h>

// GetPseudoMaskSLFCAMS: exact rank-cut selection (stable ties) + 3x3 dilation + seed map.
// x: (128,1,512,512) fp32.  out: (128,512,512) int32 {1,0,-255}.
//
//   bg(q)  <=> (u(x_q), idx_q) <= boundary key at rank 26213
//   fg(q)  <=> (u(x_q), idx_q) >= boundary key at rank 235930
// u() = sign-flip monotone float->u32 map.

#define HW      262144      // 512*512 = 2^18
#define NROW    128
#define R1_RANK 26213u      // MIN_-1
#define R2_RANK 235930u     // HW-MAX_
#define NBIN    8192        // top-13 bits of sortable u32
#define CAP     8192        // candidate capacity per (row,side); expected ~2.9K for N(0,1)
#define LCAP    1024        // third-level list capacity
#define CBLK    4096        // elements per k_collect block
#define BUFCAP  1024        // LDS staging capacity per side (expected ~45/block; overflow->global)

__device__ __forceinline__ unsigned f2u(float f) {
    unsigned b = __float_as_uint(f);
    return b ^ ((b >> 31) ? 0xFFFFFFFFu : 0x80000000u);
}

// ---------------- K1: per-row coarse histogram (top 13 bits) ----------------
// u16-packed LDS histogram (16 KB), 512 threads, prefetched loads.
// 8 chunks/row, 32768 elem/block: max per-bin count 32768 < 65536 -> u16 safe.
__global__ __launch_bounds__(512) void k_hist(const float* __restrict__ x,
                                              unsigned* __restrict__ hist) {
    __shared__ unsigned lh[NBIN / 2];   // word w = bins {2w (lo16), 2w+1 (hi16)}
    for (int i = threadIdx.x; i < NBIN / 2; i += 512) lh[i] = 0;
    __syncthreads();
    int row = blockIdx.x >> 3;
    int chunk = blockIdx.x & 7;
    const float4* p = (const float4*)(x + (size_t)row * HW + (size_t)chunk * 32768);
    float4 v = p[threadIdx.x];
    #pragma unroll 4
    for (int it = 0; it < 16; ++it) {
        float4 cur = v;
        if (it < 15) v = p[(it + 1) * 512 + threadIdx.x];
        unsigned b0 = f2u(cur.x) >> 19, b1 = f2u(cur.y) >> 19;
        unsigned b2 = f2u(cur.z) >> 19, b3 = f2u(cur.w) >> 19;
        atomicAdd(&lh[b0 >> 1], (b0 & 1) ? 65536u : 1u);
        atomicAdd(&lh[b1 >> 1], (b1 & 1) ? 65536u : 1u);
        atomicAdd(&lh[b2 >> 1], (b2 & 1) ? 65536u : 1u);
        atomicAdd(&lh[b3 >> 1], (b3 & 1) ? 65536u : 1u);
    }
    __syncthreads();
    unsigned* gh = hist + (size_t)row * NBIN;
    for (int i = threadIdx.x; i < NBIN / 2; i += 512) {
        unsigned w = lh[i];
        unsigned lo = w & 0xFFFFu, hi = w >> 16;
        if (lo) atomicAdd(&gh[2 * i], lo);
        if (hi) atomicAdd(&gh[2 * i + 1], hi);
    }
}

// ---------------- K2: find bin containing each rank + within-bin rank -------
// meta[row*4 + {0,1,2,3}] = {bin1, r1, bin2, r2}
__global__ __launch_bounds__(256) void k_findbin(const unsigned* __restrict__ hist,
                                                 unsigned* __restrict__ meta) {
    int row = blockIdx.x;
    const unsigned* h = hist + (size_t)row * NBIN;
    __shared__ unsigned psum[256];
    __shared__ unsigned excl[257];
    int base = threadIdx.x * 32;
    unsigned s = 0;
    for (int i = 0; i < 32; ++i) s += h[base + i];
    psum[threadIdx.x] = s;
    __syncthreads();
    if (threadIdx.x == 0) {
        unsigned a = 0;
        for (int t = 0; t < 256; ++t) { excl[t] = a; a += psum[t]; }
        excl[256] = a;
    }
    __syncthreads();
    for (int side = 0; side < 2; ++side) {
        unsigned R = side ? R2_RANK : R1_RANK;
        if (excl[threadIdx.x] <= R && R < excl[threadIdx.x + 1]) {
            unsigned a = excl[threadIdx.x];
            for (int i = 0; i < 32; ++i) {
                unsigned c = h[base + i];
                if (R < a + c) { meta[row * 4 + side * 2] = base + i;
                                 meta[row * 4 + side * 2 + 1] = R - a; break; }
                a += c;
            }
        }
    }
}

// ---------------- K3: collect candidates (block-aggregated, 2 atomics/block) -
__global__ __launch_bounds__(512) void k_collect(const float* __restrict__ x,
                                                 const unsigned* __restrict__ meta,
                                                 unsigned* __restrict__ cnt,
                                                 unsigned long long* __restrict__ cand) {
    __shared__ unsigned long long buf0[BUFCAP];
    __shared__ unsigned long long buf1[BUFCAP];
    __shared__ unsigned bcnt[2];
    __shared__ unsigned gbase[2];
    if (threadIdx.x < 2) bcnt[threadIdx.x] = 0;
    __syncthreads();

    size_t ebase = (size_t)blockIdx.x * CBLK;     // block-aligned, row-uniform
    int row = (int)(ebase >> 18);
    unsigned bin1 = meta[row * 4 + 0];
    unsigned bin2 = meta[row * 4 + 2];
    unsigned long long* c0 = cand + ((size_t)(row * 2 + 0)) * CAP;
    unsigned long long* c1 = cand + ((size_t)(row * 2 + 1)) * CAP;
    const float4* p = (const float4*)(x + ebase);
    #pragma unroll
    for (int j = 0; j < 2; ++j) {
        int t4 = j * 512 + threadIdx.x;
        float4 v = p[t4];
        float vv[4] = {v.x, v.y, v.z, v.w};
        unsigned eidx = (unsigned)((ebase + (size_t)t4 * 4) & (HW - 1));
        #pragma unroll
        for (int k = 0; k < 4; ++k) {
            unsigned u = f2u(vv[k]);
            unsigned bin = u >> 19;
            unsigned long long key = (((unsigned long long)u) << 32) | (eidx + k);
            if (bin == bin1) {
                unsigned s = atomicAdd(&bcnt[0], 1u);
                if (s < BUFCAP) buf0[s] = key;
                else { unsigned g = atomicAdd(&cnt[row * 2 + 0], 1u); if (g < CAP) c0[g] = key; }
            }
            if (bin == bin2) {
                unsigned s = atomicAdd(&bcnt[1], 1u);
                if (s < BUFCAP) buf1[s] = key;
                else { unsigned g = atomicAdd(&cnt[row * 2 + 1], 1u); if (g < CAP) c1[g] = key; }
            }
        }
    }
    __syncthreads();
    unsigned n0 = bcnt[0] < BUFCAP ? bcnt[0] : BUFCAP;
    unsigned n1 = bcnt[1] < BUFCAP ? bcnt[1] : BUFCAP;
    if (threadIdx.x == 0) gbase[0] = atomicAdd(&cnt[row * 2 + 0], n0);
    if (threadIdx.x == 1) gbase[1] = atomicAdd(&cnt[row * 2 + 1], n1);
    __syncthreads();
    for (unsigned i = threadIdx.x; i < n0; i += 512) {
        unsigned slot = gbase[0] + i;
        if (slot < CAP) c0[slot] = buf0[i];
    }
    for (unsigned i = threadIdx.x; i < n1; i += 512) {
        unsigned slot = gbase[1] + i;
        if (slot < CAP) c1[slot] = buf1[i];
    }
}

// ---------------- K4: exact boundary key per (row,side) ---------------------
// thr[row*4 + {0,1,2,3}] = {T1u, cutIdx1, T2u, cutIdx2}
__global__ __launch_bounds__(256) void k_select(const unsigned* __restrict__ meta,
                                                const unsigned* __restrict__ cnt,
                                                const unsigned long long* __restrict__ cand,
                                                unsigned* __restrict__ thr) {
    int row = blockIdx.x >> 1, side = blockIdx.x & 1;
    unsigned m = cnt[row * 2 + side]; if (m > CAP) m = CAP;
    unsigned r = meta[row * 4 + side * 2 + 1];
    const unsigned long long* ck = cand + ((size_t)(row * 2 + side)) * CAP;

    __shared__ unsigned h2[NBIN];
    __shared__ unsigned psum[256];
    __shared__ unsigned excl[257];
    __shared__ unsigned long long list[LCAP];
    __shared__ unsigned listCnt, subbin_s, rprime_s;
    for (int i = threadIdx.x; i < NBIN; i += 256) h2[i] = 0;
    if (threadIdx.x == 0) listCnt = 0;
    __syncthreads();
    // second-level histogram over bits 18..6 (all candidates share bits 31..19)
    for (unsigned i = threadIdx.x; i < m; i += 256) {
        unsigned u = (unsigned)(ck[i] >> 32);
        atomicAdd(&h2[(u >> 6) & (NBIN - 1)], 1u);
    }
    __syncthreads();
    int base = threadIdx.x * 32;
    unsigned s = 0;
    for (int i = 0; i < 32; ++i) s += h2[base + i];
    psum[threadIdx.x] = s;
    __syncthreads();
    if (threadIdx.x == 0) {
        unsigned a = 0;
        for (int t = 0; t < 256; ++t) { excl[t] = a; a += psum[t]; }
        excl[256] = a;
    }
    __syncthreads();
    if (excl[threadIdx.x] <= r && r < excl[threadIdx.x + 1]) {
        unsigned a = excl[threadIdx.x];
        for (int i = 0; i < 32; ++i) {
            unsigned c = h2[base + i];
            if (r < a + c) { subbin_s = (unsigned)(base + i); rprime_s = r - a; break; }
            a += c;
        }
    }
    __syncthreads();
    unsigned sb = subbin_s, rp = rprime_s;
    // third level: gather the (few) keys in the cut sub-bin, exact rank among them
    for (unsigned i = threadIdx.x; i < m; i += 256) {
        unsigned long long k = ck[i];
        if ((((unsigned)(k >> 32)) >> 6 & (NBIN - 1)) == sb) {
            unsigned slot = atomicAdd(&listCnt, 1u);
            if (slot < LCAP) list[slot] = k;
        }
    }
    __syncthreads();
    unsigned lm = listCnt; if (lm > LCAP) lm = LCAP;
    for (unsigned i = threadIdx.x; i < lm; i += 256) {
        unsigned long long ki = list[i];
        unsigned c = 0;
        for (unsigned j = 0; j < lm; ++j) c += (list[j] < ki);
        if (c == rp) {
            thr[row * 4 + side * 2]     = (unsigned)(ki >> 32);
            thr[row * 4 + side * 2 + 1] = (unsigned)ki;
        }
    }
}

// ---------------- K5: fused seed codes + 3x3 dilation + int32 output --------
__global__ __launch_bounds__(256) void k_seed(const float* __restrict__ x,
                                              const unsigned* __restrict__ thr,
                                              int* __restrict__ out) {
    int row = blockIdx.z;
    int tx0 = blockIdx.x * 32, ty0 = blockIdx.y * 32;
    __shared__ unsigned char code[34 * 36];   // [ly][lx], stride 36
    unsigned T1 = thr[row * 4 + 0], C1 = thr[row * 4 + 1];
    unsigned T2 = thr[row * 4 + 2], C2 = thr[row * 4 + 3];
    const float* xr = x + (size_t)row * HW;
    for (int t = threadIdx.x; t < 34 * 34; t += 256) {
        int ly = t / 34, lx = t % 34;
        int gy = ty0 + ly - 1, gx = tx0 + lx - 1;
        unsigned char c = 0;
        if (gx >= 0 && gx < 512 && gy >= 0 && gy < 512) {
            unsigned idx = (unsigned)(gy * 512 + gx);
            unsigned u = f2u(xr[idx]);
            bool bg = (u < T1) || (u == T1 && idx <= C1);
            bool fg = (u > T2) || (u == T2 && idx >= C2);
            c = (unsigned char)((bg ? 1 : 0) | (fg ? 2 : 0));
        }
        code[ly * 36 + lx] = c;
    }
    __syncthreads();
    int lx = threadIdx.x & 31;
    int ly0 = (threadIdx.x >> 5) * 4;
    #define OR3(r) ((unsigned)(code[(r) * 36 + lx] | code[(r) * 36 + lx + 1] | code[(r) * 36 + lx + 2]))
    unsigned c0 = OR3(ly0), c1 = OR3(ly0 + 1);
    for (int k = 0; k < 4; ++k) {
        unsigned c2 = OR3(ly0 + k + 2);
        unsigned mm = c0 | c1 | c2;
        bool bgd = mm & 1, fgd = mm & 2;
        int o = ((bgd ^ fgd) != 0) ? (fgd ? 1 : 0) : -255;
        out[(size_t)row * HW + (size_t)(ty0 + ly0 + k) * 512 + (tx0 + lx)] = o;
        c0 = c1; c1 = c2;
    }
    #undef OR3
}

extern "C" void kernel_launch(void* const* d_in, const int* in_sizes, int n_in,
                              void* d_out, int out_size, void* d_ws, size_t ws_size,
                              hipStream_t stream) {
    const float* x = (const float*)d_in[0];
    int* out = (int*)d_out;

    // workspace layout (needs ~21 MB)
    char* ws = (char*)d_ws;
    unsigned* hist = (unsigned*)ws;                                   // 4 MB
    unsigned* cnt  = (unsigned*)(ws + (size_t)NROW * NBIN * 4);       // 1 KB
    unsigned* meta = (unsigned*)(ws + (size_t)NROW * NBIN * 4 + 1024);          // 2 KB
    unsigned* thr  = (unsigned*)(ws + (size_t)NROW * NBIN * 4 + 3072);          // 2 KB
    unsigned long long* cand =
        (unsigned long long*)(ws + (size_t)NROW * NBIN * 4 + 8192);   // 16 MB

    // zero hist + counters (contiguous prefix of ws)
    hipMemsetAsync(d_ws, 0, (size_t)NROW * NBIN * 4 + 1024, stream);

    k_hist<<<NROW * 8, 512, 0, stream>>>(x, hist);
    k_findbin<<<NROW, 256, 0, stream>>>(hist, meta);
    k_collect<<<(NROW * HW) / CBLK, 512, 0, stream>>>(x, meta, cnt, cand);
    k_select<<<NROW * 2, 256, 0, stream>>>(meta, cnt, cand, thr);
    k_seed<<<dim3(16, 16, NROW), 256, 0, stream>>>(x, thr, out);
}